// Round 11
// baseline (660.344 us; speedup 1.0000x reference)
//
#include <hip/hip_runtime.h>
#include <hip/hip_bf16.h>
#include <math.h>
#include <string.h>

#define NA_N 50000
#define NB_N 50000
#define DIN_N 128
#define HID_N 256
#define NE_N 1000000

#define BSHIFT 9
#define BSIZE (1 << BSHIFT)
#define NBUCK ((NA_N + BSIZE - 1) >> BSHIFT)       // 98
#define CHUNK 4096
#define CGRID ((NE_N + CHUNK - 1) / CHUNK)         // 245

// prep_kernel block ranges
#define NF_BLK (NA_N * DIN_N / 4 / 256)            // 6250 per array
#define NT_BLK 2048                                // 8 weights x 256
#define NH_BLK (2 * CGRID)                         // 490

typedef short short8 __attribute__((ext_vector_type(8)));
typedef float f32x4 __attribute__((ext_vector_type(4)));
typedef unsigned int uint2e __attribute__((ext_vector_type(2)));

#define GLDS16(gp, lp) __builtin_amdgcn_global_load_lds( \
    (const __attribute__((address_space(1))) void*)(gp), \
    (__attribute__((address_space(3))) void*)(lp), 16, 0, 0)

static __device__ __forceinline__ float lrelu(float x) {
    return x >= 0.0f ? x : 0.01f * x;
}

static __device__ __forceinline__ unsigned short f2bf(float f) {
    __hip_bfloat16 h = __float2bfloat16(f);   // RNE
    unsigned short u;
    memcpy(&u, &h, 2);
    return u;
}

// chunk swizzle for 64B LDS rows of 4x16B chunks (staged tiles)
static __device__ __forceinline__ int swz(int r) { return (r & 3) ^ ((r >> 2) & 3); }

// sliced (slice-major) feature layout: 8 slices of SW cols; slice block = [n][SW] ushorts.
// D=256 -> SW=32 (one BK=32 k-step per slice); D=128 -> SW=16 (k-step spans 2 slices).
template <int D>
static __device__ __forceinline__ const unsigned short*
sliced_addr(const unsigned short* base, int n, int row, int k0, int chunk /*0..3, 8 ushorts each*/) {
    if constexpr (D == 256) {
        return base + (size_t)(k0 >> 5) * n * 32 + (size_t)row * 32 + chunk * 8;
    } else {
        int slice = (k0 >> 4) + (chunk >> 1);
        return base + (size_t)slice * n * 16 + (size_t)row * 16 + (chunk & 1) * 8;
    }
}

// ---------------- merged prep: f2bf (sliced out) + 8 weight transposes + 2 coarse hists ----------------

struct TW { const float* W; unsigned short* T; int D; };

struct PrepArgs {
    const float* xa; unsigned short* xa_bf;
    const float* xb; unsigned short* xb_bf;
    TW t[8];
    const int* dstA; const int* dstB;
    int* ghA; int* ghB;
};

__global__ __launch_bounds__(256)
void prep_kernel(PrepArgs A) {
    int bid = blockIdx.x;
    const int tid = threadIdx.x;
    if (bid < 2 * NF_BLK) {                        // fp32 -> bf16, slice-major out (SW=16)
        int which = bid >= NF_BLK;
        const float* in = which ? A.xb : A.xa;
        unsigned short* out = which ? A.xb_bf : A.xa_bf;
        int i = (bid - which * NF_BLK) * 256 + tid;   // float4 index
        float4 v = ((const float4*)in)[i];
        ushort4 b;
        b.x = f2bf(v.x); b.y = f2bf(v.y); b.z = f2bf(v.z); b.w = f2bf(v.w);
        int row = i >> 5, c4 = i & 31;             // 32 float4s per 128-col row
        unsigned short* dst = out + (size_t)(c4 >> 2) * (NA_N * 16) + (size_t)row * 16 + (c4 & 3) * 4;
        *(ushort4*)dst = b;
        return;
    }
    bid -= 2 * NF_BLK;
    if (bid < NT_BLK) {                            // weight transpose W[k][c] -> T[c][k] bf16
        TW t = A.t[bid >> 8];
        int wg = (bid & 255) * 4 + (tid >> 6);
        int lane = tid & 63;
        int kchunks = t.D >> 6;
        int c = wg / kchunks;
        int kc = wg - c * kchunks;
        int k = kc * 64 + lane;
        if (c < 256) t.T[(size_t)c * t.D + k] = f2bf(t.W[(size_t)k * 256 + c]);
        return;
    }
    bid -= NT_BLK;
    {                                              // coarse hist (bucket = dst >> BSHIFT)
        int which = bid >= CGRID;
        const int* dst = which ? A.dstB : A.dstA;
        int* ghist = which ? A.ghB : A.ghA;
        int base = (bid - which * CGRID) * CHUNK;
        __shared__ int lc[NBUCK];
        for (int i = tid; i < NBUCK; i += 256) lc[i] = 0;
        __syncthreads();
        int end = min(base + CHUNK, NE_N);
        for (int i = base + tid; i < end; i += 256)
            atomicAdd(&lc[dst[i] >> BSHIFT], 1);
        __syncthreads();
        for (int i = tid; i < NBUCK; i += 256)
            if (lc[i]) atomicAdd(&ghist[i], lc[i]);
    }
}

// ---------------- bucketed CSR build (merged over both edge types) ----------------
// bucketed entry: (dst_local << 17) | src

__global__ void bucket_scan2(const int* __restrict__ ghA, int* __restrict__ cbA, int* __restrict__ curA,
                             const int* __restrict__ ghB, int* __restrict__ cbB, int* __restrict__ curB) {
    const int* ghist = blockIdx.x ? ghB : ghA;
    int* cbase = blockIdx.x ? cbB : cbA;
    int* cursor = blockIdx.x ? curB : curA;
    int tid = threadIdx.x;
    int v = (tid < NBUCK) ? ghist[tid] : 0;
    int incl = v;
    #pragma unroll
    for (int m = 1; m < 64; m <<= 1) {
        int o = __shfl_up(incl, m, 64);
        if ((tid & 63) >= m) incl += o;
    }
    __shared__ int wsum[2];
    if ((tid & 63) == 63) wsum[tid >> 6] = incl;
    __syncthreads();
    if (tid >= 64) incl += wsum[0];
    if (tid < NBUCK) {
        cbase[tid] = incl - v;
        cursor[tid] = incl - v;
    }
    if (tid == 127) cbase[NBUCK] = incl;
}

__global__ __launch_bounds__(256)
void coarse_scatter2(const int* __restrict__ eiA, const int* __restrict__ eiB, int E,
                     int* __restrict__ curA, unsigned int* __restrict__ bkA,
                     int* __restrict__ curB, unsigned int* __restrict__ bkB) {
    const int* src = blockIdx.y ? eiB : eiA;
    const int* dst = src + E;
    int* cursor = blockIdx.y ? curB : curA;
    unsigned int* bucketed = blockIdx.y ? bkB : bkA;
    __shared__ int lc[NBUCK];
    __shared__ int gb[NBUCK];
    for (int i = threadIdx.x; i < NBUCK; i += 256) lc[i] = 0;
    __syncthreads();
    int base = blockIdx.x * CHUNK;
    int end = min(base + CHUNK, E);
    for (int i = base + threadIdx.x; i < end; i += 256)
        atomicAdd(&lc[dst[i] >> BSHIFT], 1);
    __syncthreads();
    for (int i = threadIdx.x; i < NBUCK; i += 256) {
        int c = lc[i];
        gb[i] = c ? atomicAdd(&cursor[i], c) : 0;
        lc[i] = 0;
    }
    __syncthreads();
    for (int i = base + threadIdx.x; i < end; i += 256) {
        int d = dst[i];
        int bk = d >> BSHIFT;
        int p = atomicAdd(&lc[bk], 1);
        bucketed[(size_t)gb[bk] + p] =
            ((unsigned int)(d - (bk << BSHIFT)) << 17) | (unsigned int)src[i];
    }
}

__global__ __launch_bounds__(256)
void fine_scatter2(const unsigned int* __restrict__ bkA, const int* __restrict__ cbA,
                   int* __restrict__ offsA, int* __restrict__ ssrcA,
                   const unsigned int* __restrict__ bkB, const int* __restrict__ cbB,
                   int* __restrict__ offsB, int* __restrict__ ssrcB, int n, int E) {
    const unsigned int* bucketed = blockIdx.y ? bkB : bkA;
    const int* cbase = blockIdx.y ? cbB : cbA;
    int* offs = blockIdx.y ? offsB : offsA;
    int* ssrc = blockIdx.y ? ssrcB : ssrcA;
    int bk = blockIdx.x;
    int ebeg = cbase[bk], eend = cbase[bk + 1];
    int d0 = bk << BSHIFT;
    __shared__ int dc[BSIZE];
    __shared__ int wp[4];
    int tid = threadIdx.x;
    for (int i = tid; i < BSIZE; i += 256) dc[i] = 0;
    __syncthreads();
    for (int i = ebeg + tid; i < eend; i += 256) {
        atomicAdd(&dc[bucketed[i] >> 17], 1);
    }
    __syncthreads();
    int a = dc[2 * tid], b = dc[2 * tid + 1];
    int s = a + b;
    int incl = s;
    #pragma unroll
    for (int m = 1; m < 64; m <<= 1) {
        int o = __shfl_up(incl, m, 64);
        if ((tid & 63) >= m) incl += o;
    }
    if ((tid & 63) == 63) wp[tid >> 6] = incl;
    __syncthreads();
    int add = 0;
    for (int w0 = 0; w0 < (tid >> 6); ++w0) add += wp[w0];
    incl += add;
    int excl = incl - s;
    dc[2 * tid] = excl;
    dc[2 * tid + 1] = excl + a;
    int d = d0 + 2 * tid;
    if (d < n) offs[d] = ebeg + excl;
    if (d + 1 < n) offs[d + 1] = ebeg + excl + a;
    if (bk == (int)gridDim.x - 1 && tid == 0) offs[n] = E;
    __syncthreads();
    for (int i = ebeg + tid; i < eend; i += 256) {
        unsigned int e = bucketed[i];
        int p = atomicAdd(&dc[e >> 17], 1);
        ssrc[ebeg + p] = (int)(e & 0x1ffffu);
    }
}

// -------- XCD-sliced aggregation --------
// slice = blockIdx.x & 7 (round-robin XCD dispatch -> slice pinned to one XCD, L2-resident).
// Each wave handles 8 destinations; LPE lanes per edge (8B each); U load-steps in flight.

struct AggSP {
    const unsigned short* xsrc;   // sliced layout
    const int* ssrc;
    const int* offs;
    unsigned short* mean;         // sliced layout
};

template <int SW>
__global__ __launch_bounds__(256)
void agg_slice(AggSP p0, AggSP p1, int n, int grp_per_type) {
    int bid = blockIdx.x;
    const int slice = bid & 7;
    int rest = bid >> 3;
    int type = rest >= grp_per_type;
    int group = rest - (type ? grp_per_type : 0);
    AggSP P = type ? p1 : p0;
    constexpr int LPE = SW / 4;       // lanes per edge (8B per lane)
    constexpr int EPW = 64 / LPE;     // edges per load step
    constexpr int U = (SW == 32) ? 4 : 2;
    const int lane = threadIdx.x & 63;
    const int wv = threadIdx.x >> 6;
    const int grp = lane / LPE;
    const int pos = lane % LPE;
    const unsigned short* sbase = P.xsrc + (size_t)slice * n * SW + pos * 4;
    unsigned short* mbase = P.mean + (size_t)slice * n * SW + pos * 4;

    #pragma unroll 1
    for (int d = 0; d < 8; ++d) {
        int w = group * 32 + wv * 8 + d;
        if (w >= n) break;
        const int beg = P.offs[w], end = P.offs[w + 1];
        float acc[4] = {0.f, 0.f, 0.f, 0.f};
        for (int e = beg; e < end; e += EPW * U) {
            int idx[U];
            float wt[U];
            #pragma unroll
            for (int u = 0; u < U; ++u) {
                int ee = e + u * EPW + grp;
                idx[u] = __builtin_nontemporal_load(&P.ssrc[ee < end ? ee : end - 1]);
                wt[u] = (ee < end) ? 1.0f : 0.0f;
            }
            uint2e v[U];
            #pragma unroll
            for (int u = 0; u < U; ++u)
                v[u] = *(const uint2e*)(sbase + (size_t)idx[u] * SW);
            #pragma unroll
            for (int u = 0; u < U; ++u) {
                acc[0] = fmaf(wt[u], __uint_as_float(v[u].x << 16), acc[0]);
                acc[1] = fmaf(wt[u], __uint_as_float(v[u].x & 0xffff0000u), acc[1]);
                acc[2] = fmaf(wt[u], __uint_as_float(v[u].y << 16), acc[2]);
                acc[3] = fmaf(wt[u], __uint_as_float(v[u].y & 0xffff0000u), acc[3]);
            }
        }
        #pragma unroll
        for (int m = LPE; m < 64; m <<= 1)
            #pragma unroll
            for (int c = 0; c < 4; ++c)
                acc[c] += __shfl_xor(acc[c], m, 64);
        if (lane < LPE) {
            float inv = 1.0f / fmaxf((float)(end - beg), 1.0f);
            uint2e o;
            o.x = ((unsigned int)f2bf(acc[1] * inv) << 16) | f2bf(acc[0] * inv);
            o.y = ((unsigned int)f2bf(acc[3] * inv) << 16) | f2bf(acc[2] * inv);
            __builtin_nontemporal_store(o, (uint2e*)(mbase + (size_t)w * SW));
        }
    }
}

// ------- fused MFMA dual-GEMM + bias + L2-normalize + leaky_relu -------
// BM=128, BN=256, BK=32, 512 threads. A (mean) and X (roots) in sliced layouts;
// glds staging with chunk-XOR swizzle; layer-0 writes h sliced, layer-1 writes fp32 rows.

struct GP {
    const unsigned short* A;
    const unsigned short* X;
    const unsigned short* Wtl;
    const unsigned short* Wtr;
    const float* bias;
    float* outf;
    unsigned short* outb;
};

template <int D, bool BF16OUT>
__global__ __launch_bounds__(512)
void mfma_gemm2(GP p0, GP p1, int n) {
    GP P = blockIdx.y ? p1 : p0;
    constexpr int BM = 128, BK = 32;
    __shared__ __align__(16) unsigned short Asl[BM * BK];     //  8 KB
    __shared__ __align__(16) unsigned short Wsl[256 * BK];    // 16 KB
    __shared__ float red[4][BM];
    __shared__ float invn[BM];

    const int tid = threadIdx.x;
    const int wid = tid >> 6;
    const int lane = tid & 63;
    const int wr = wid >> 2, wc = wid & 3;
    const int cl = lane & 15, g = lane >> 4;
    const int row0 = blockIdx.x * BM;
    const bool full = (row0 + BM <= n);

    f32x4 acc[4][4];
    #pragma unroll
    for (int m = 0; m < 4; ++m)
        #pragma unroll
        for (int nn = 0; nn < 4; ++nn)
            acc[m][nn] = (f32x4){0.f, 0.f, 0.f, 0.f};

    #pragma unroll
    for (int pass = 0; pass < 2; ++pass) {
        const unsigned short* __restrict__ M = pass ? P.X : P.A;
        const unsigned short* __restrict__ Wt = pass ? P.Wtr : P.Wtl;
        for (int k0 = 0; k0 < D; k0 += BK) {
            __syncthreads();
            if (full) {
                int r = wid * 16 + (lane >> 2);
                int c = lane & 3;
                GLDS16(sliced_addr<D>(M, n, row0 + r, k0, c ^ swz(r)), &Asl[wid * 512]);
            } else {
                int r = tid >> 2, c = tid & 3;
                short8 v = {0, 0, 0, 0, 0, 0, 0, 0};
                if (row0 + r < n)
                    v = *(const short8*)sliced_addr<D>(M, n, row0 + r, k0, c ^ swz(r));
                *(short8*)(&Asl[r * 32 + (c << 3)]) = v;
            }
            #pragma unroll
            for (int q = 0; q < 2; ++q) {
                int rw = q * 128 + wid * 16 + (lane >> 2);
                int c = lane & 3;
                const unsigned short* src = Wt + (size_t)rw * D + k0 + ((c ^ swz(rw)) << 3);
                GLDS16(src, &Wsl[(q * 128 + wid * 16) * 32]);
            }
            __syncthreads();
            short8 af[4], bfr[4];
            #pragma unroll
            for (int m = 0; m < 4; ++m) {
                int R = wr * 64 + m * 16 + cl;
                af[m] = *(const short8*)(&Asl[R * 32 + ((g ^ swz(R)) << 3)]);
            }
            #pragma unroll
            for (int nn = 0; nn < 4; ++nn) {
                int C = wc * 64 + nn * 16 + cl;
                bfr[nn] = *(const short8*)(&Wsl[C * 32 + ((g ^ swz(C)) << 3)]);
            }
            #pragma unroll
            for (int m = 0; m < 4; ++m)
                #pragma unroll
                for (int nn = 0; nn < 4; ++nn)
                    acc[m][nn] = __builtin_amdgcn_mfma_f32_16x16x32_bf16(
                        af[m], bfr[nn], acc[m][nn], 0, 0, 0);
        }
    }

    // ---- epilogue: bias, row L2-norm, leaky-relu ----
    float bv[4];
    #pragma unroll
    for (int nn = 0; nn < 4; ++nn) bv[nn] = P.bias[wc * 64 + nn * 16 + cl];

    float ss[4][4];
    #pragma unroll
    for (int m = 0; m < 4; ++m)
        #pragma unroll
        for (int r = 0; r < 4; ++r) {
            float s = 0.f;
            #pragma unroll
            for (int nn = 0; nn < 4; ++nn) {
                acc[m][nn][r] += bv[nn];
                s = fmaf(acc[m][nn][r], acc[m][nn][r], s);
            }
            ss[m][r] = s;
        }
    #pragma unroll
    for (int mask = 1; mask < 16; mask <<= 1)
        #pragma unroll
        for (int m = 0; m < 4; ++m)
            #pragma unroll
            for (int r = 0; r < 4; ++r)
                ss[m][r] += __shfl_xor(ss[m][r], mask, 64);
    if (cl == 0) {
        #pragma unroll
        for (int m = 0; m < 4; ++m)
            #pragma unroll
            for (int r = 0; r < 4; ++r)
                red[wc][wr * 64 + m * 16 + g * 4 + r] = ss[m][r];
    }
    __syncthreads();
    if (tid < BM) {
        float tot = red[0][tid] + red[1][tid] + red[2][tid] + red[3][tid];
        invn[tid] = 1.0f / fmaxf(sqrtf(tot), 1e-12f);
    }
    __syncthreads();
    #pragma unroll
    for (int m = 0; m < 4; ++m)
        #pragma unroll
        for (int r = 0; r < 4; ++r) {
            int row = wr * 64 + m * 16 + g * 4 + r;
            if (row0 + row < n) {
                float iv = invn[row];
                #pragma unroll
                for (int nn = 0; nn < 4; ++nn) {
                    float o = lrelu(acc[m][nn][r] * iv);
                    if constexpr (BF16OUT) {
                        // sliced h output (SW=32): slice = col>>5
                        int slice = wc * 2 + (nn >> 1);
                        size_t off = (size_t)slice * n * 32 + (size_t)(row0 + row) * 32 +
                                     (nn & 1) * 16 + cl;
                        P.outb[off] = f2bf(o);
                    } else {
                        P.outf[(size_t)(row0 + row) * HID_N + wc * 64 + nn * 16 + cl] = o;
                    }
                }
            }
        }
}

// ---------------- launcher ----------------

extern "C" void kernel_launch(void* const* d_in, const int* in_sizes, int n_in,
                              void* d_out, int out_size, void* d_ws, size_t ws_size,
                              hipStream_t stream) {
    const float* xa = (const float*)d_in[0];
    const float* xb = (const float*)d_in[1];
    const int* ei_ab = (const int*)d_in[2];
    const int* ei_ba = (const int*)d_in[3];
    const float* Wl0_ab = (const float*)d_in[4];
    const float* Wr0_ab = (const float*)d_in[5];
    const float* b0_ab = (const float*)d_in[6];
    const float* Wl0_ba = (const float*)d_in[7];
    const float* Wr0_ba = (const float*)d_in[8];
    const float* b0_ba = (const float*)d_in[9];
    const float* Wl1_ab = (const float*)d_in[10];
    const float* Wr1_ab = (const float*)d_in[11];
    const float* b1_ab = (const float*)d_in[12];
    const float* Wl1_ba = (const float*)d_in[13];
    const float* Wr1_ba = (const float*)d_in[14];
    const float* b1_ba = (const float*)d_in[15];

    float* out_a = (float*)d_out;
    float* out_b = out_a + (size_t)NA_N * HID_N;

    char* w = (char*)d_ws;
    auto carve = [&](size_t bytes) -> char* {
        char* p = w;
        w += (bytes + 255) & ~(size_t)255;
        return p;
    };
    unsigned short* agg1 = (unsigned short*)carve((size_t)NB_N * HID_N * 2);
    unsigned short* agg2 = (unsigned short*)carve((size_t)NA_N * HID_N * 2);
    unsigned int* bucketed_b = (unsigned int*)agg1;   // aliases agg1 (dead before aggs)
    unsigned int* bucketed_a = (unsigned int*)agg2;
    unsigned short* xa_bf = (unsigned short*)carve((size_t)NA_N * DIN_N * 2);
    unsigned short* xb_bf = (unsigned short*)carve((size_t)NB_N * DIN_N * 2);
    unsigned short* ha_bf = (unsigned short*)carve((size_t)NA_N * HID_N * 2);
    unsigned short* hb_bf = (unsigned short*)carve((size_t)NB_N * HID_N * 2);
    int* off_b = (int*)carve((size_t)(NB_N + 1) * 4);
    int* off_a = (int*)carve((size_t)(NA_N + 1) * 4);
    int* ghist_b = (int*)carve(2 * NBUCK * 4);
    int* ghist_a = ghist_b + NBUCK;
    int* cbase_b = (int*)carve((NBUCK + 1) * 4);
    int* cbase_a = (int*)carve((NBUCK + 1) * 4);
    int* cursor_b = (int*)carve(NBUCK * 4);
    int* cursor_a = (int*)carve(NBUCK * 4);
    int* ssrc_ab = (int*)carve((size_t)NE_N * 4);
    int* ssrc_ba = (int*)carve((size_t)NE_N * 4);
    unsigned short* wt_l0ab = (unsigned short*)carve((size_t)DIN_N * 256 * 2);
    unsigned short* wt_r0ab = (unsigned short*)carve((size_t)DIN_N * 256 * 2);
    unsigned short* wt_l0ba = (unsigned short*)carve((size_t)DIN_N * 256 * 2);
    unsigned short* wt_r0ba = (unsigned short*)carve((size_t)DIN_N * 256 * 2);
    unsigned short* wt_l1ab = (unsigned short*)carve((size_t)HID_N * 256 * 2);
    unsigned short* wt_r1ab = (unsigned short*)carve((size_t)HID_N * 256 * 2);
    unsigned short* wt_l1ba = (unsigned short*)carve((size_t)HID_N * 256 * 2);
    unsigned short* wt_r1ba = (unsigned short*)carve((size_t)HID_N * 256 * 2);

    hipMemsetAsync(ghist_b, 0, 2 * NBUCK * 4, stream);

    {
        PrepArgs A;
        A.xa = xa; A.xa_bf = xa_bf;
        A.xb = xb; A.xb_bf = xb_bf;
        A.t[0] = {Wl0_ab, wt_l0ab, DIN_N}; A.t[1] = {Wr0_ab, wt_r0ab, DIN_N};
        A.t[2] = {Wl0_ba, wt_l0ba, DIN_N}; A.t[3] = {Wr0_ba, wt_r0ba, DIN_N};
        A.t[4] = {Wl1_ab, wt_l1ab, HID_N}; A.t[5] = {Wr1_ab, wt_r1ab, HID_N};
        A.t[6] = {Wl1_ba, wt_l1ba, HID_N}; A.t[7] = {Wr1_ba, wt_r1ba, HID_N};
        A.dstA = ei_ab + NE_N; A.dstB = ei_ba + NE_N;
        A.ghA = ghist_b; A.ghB = ghist_a;
        prep_kernel<<<2 * NF_BLK + NT_BLK + NH_BLK, 256, 0, stream>>>(A);
    }

    bucket_scan2<<<2, 128, 0, stream>>>(ghist_b, cbase_b, cursor_b, ghist_a, cbase_a, cursor_a);
    {
        dim3 g(CGRID, 2);
        coarse_scatter2<<<g, 256, 0, stream>>>(ei_ab, ei_ba, NE_N,
                                               cursor_b, bucketed_b, cursor_a, bucketed_a);
    }
    {
        dim3 g(NBUCK, 2);
        fine_scatter2<<<g, 256, 0, stream>>>(bucketed_b, cbase_b, off_b, ssrc_ab,
                                             bucketed_a, cbase_a, off_a, ssrc_ba, NA_N, NE_N);
    }

    const int GRP32 = (NA_N + 31) / 32;            // 1563 groups of 32 dsts per type
    const int gagg = 2 * GRP32 * 8;
    const dim3 ggemm((NA_N + 127) / 128, 2);

    // ---- layer 0 (D = 128): gather x -> mean (sliced) -> GEMM -> h (sliced bf16) ----
    agg_slice<16><<<gagg, 256, 0, stream>>>(
        AggSP{xa_bf, ssrc_ab, off_b, agg1}, AggSP{xb_bf, ssrc_ba, off_a, agg2}, NA_N, GRP32);
    mfma_gemm2<DIN_N, true><<<ggemm, 512, 0, stream>>>(
        GP{agg1, xb_bf, wt_l0ab, wt_r0ab, b0_ab, nullptr, hb_bf},
        GP{agg2, xa_bf, wt_l0ba, wt_r0ba, b0_ba, nullptr, ha_bf}, NA_N);

    // ---- layer 1 (D = 256): gather h -> mean (sliced) -> GEMM -> out (fp32 rows) ----
    agg_slice<32><<<gagg, 256, 0, stream>>>(
        AggSP{ha_bf, ssrc_ab, off_b, agg1}, AggSP{hb_bf, ssrc_ba, off_a, agg2}, NA_N, GRP32);
    mfma_gemm2<HID_N, false><<<ggemm, 512, 0, stream>>>(
        GP{agg1, hb_bf, wt_l1ab, wt_r1ab, b1_ab, out_b, nullptr},
        GP{agg2, ha_bf, wt_l1ba, wt_r1ba, b1_ba, out_a, nullptr}, NA_N);
}

// Round 12
// 422.471 us; speedup vs baseline: 1.5630x; 1.5630x over previous
//
#include <hip/hip_runtime.h>
#include <hip/hip_bf16.h>
#include <math.h>
#include <string.h>

#define NA_N 50000
#define NB_N 50000
#define DIN_N 128
#define HID_N 256
#define NE_N 1000000

#define BSHIFT 9
#define BSIZE (1 << BSHIFT)
#define NBUCK ((NA_N + BSIZE - 1) >> BSHIFT)       // 98
#define CHUNK 4096
#define CGRID ((NE_N + CHUNK - 1) / CHUNK)         // 245

// prep_kernel block ranges
#define NF_BLK (NA_N * DIN_N / 4 / 256)            // 6250 per array
#define NT_BLK 2048                                // 8 weights x 256
#define NH_BLK (2 * CGRID)                         // 490

typedef short short8 __attribute__((ext_vector_type(8)));
typedef float f32x4 __attribute__((ext_vector_type(4)));
typedef unsigned int uint4v __attribute__((ext_vector_type(4)));

#define GLDS16(gp, lp) __builtin_amdgcn_global_load_lds( \
    (const __attribute__((address_space(1))) void*)(gp), \
    (__attribute__((address_space(3))) void*)(lp), 16, 0, 0)

static __device__ __forceinline__ float lrelu(float x) {
    return x >= 0.0f ? x : 0.01f * x;
}

static __device__ __forceinline__ unsigned short f2bf(float f) {
    __hip_bfloat16 h = __float2bfloat16(f);   // RNE
    unsigned short u;
    memcpy(&u, &h, 2);
    return u;
}

// chunk swizzle for 64B LDS rows of 4x16B chunks (staged tiles)
static __device__ __forceinline__ int swz(int r) { return (r & 3) ^ ((r >> 2) & 3); }

// ---------------- merged prep: f2bf (2 arrays) + 8 weight transposes + 2 coarse hists ----------------

struct TW { const float* W; unsigned short* T; int D; };

struct PrepArgs {
    const float* xa; unsigned short* xa_bf;
    const float* xb; unsigned short* xb_bf;
    TW t[8];
    const int* dstA; const int* dstB;
    int* ghA; int* ghB;
};

__global__ __launch_bounds__(256)
void prep_kernel(PrepArgs A) {
    int bid = blockIdx.x;
    const int tid = threadIdx.x;
    if (bid < 2 * NF_BLK) {                        // fp32 -> bf16 convert
        int which = bid >= NF_BLK;
        const float* in = which ? A.xb : A.xa;
        unsigned short* out = which ? A.xb_bf : A.xa_bf;
        int i = (bid - which * NF_BLK) * 256 + tid;
        float4 v = ((const float4*)in)[i];
        ushort4 b;
        b.x = f2bf(v.x); b.y = f2bf(v.y); b.z = f2bf(v.z); b.w = f2bf(v.w);
        ((ushort4*)out)[i] = b;
        return;
    }
    bid -= 2 * NF_BLK;
    if (bid < NT_BLK) {                            // weight transpose W[k][c] -> T[c][k] bf16
        TW t = A.t[bid >> 8];
        int wg = (bid & 255) * 4 + (tid >> 6);
        int lane = tid & 63;
        int kchunks = t.D >> 6;
        int c = wg / kchunks;
        int kc = wg - c * kchunks;
        int k = kc * 64 + lane;
        if (c < 256) t.T[(size_t)c * t.D + k] = f2bf(t.W[(size_t)k * 256 + c]);
        return;
    }
    bid -= NT_BLK;
    {                                              // coarse hist (bucket = dst >> BSHIFT)
        int which = bid >= CGRID;
        const int* dst = which ? A.dstB : A.dstA;
        int* ghist = which ? A.ghB : A.ghA;
        int base = (bid - which * CGRID) * CHUNK;
        __shared__ int lc[NBUCK];
        for (int i = tid; i < NBUCK; i += 256) lc[i] = 0;
        __syncthreads();
        int end = min(base + CHUNK, NE_N);
        for (int i = base + tid; i < end; i += 256)
            atomicAdd(&lc[dst[i] >> BSHIFT], 1);
        __syncthreads();
        for (int i = tid; i < NBUCK; i += 256)
            if (lc[i]) atomicAdd(&ghist[i], lc[i]);
    }
}

// ---------------- bucketed CSR build (merged over both edge types) ----------------
// bucketed entry: (dst_local << 17) | src

__global__ void bucket_scan2(const int* __restrict__ ghA, int* __restrict__ cbA, int* __restrict__ curA,
                             const int* __restrict__ ghB, int* __restrict__ cbB, int* __restrict__ curB) {
    const int* ghist = blockIdx.x ? ghB : ghA;
    int* cbase = blockIdx.x ? cbB : cbA;
    int* cursor = blockIdx.x ? curB : curA;
    int tid = threadIdx.x;
    int v = (tid < NBUCK) ? ghist[tid] : 0;
    int incl = v;
    #pragma unroll
    for (int m = 1; m < 64; m <<= 1) {
        int o = __shfl_up(incl, m, 64);
        if ((tid & 63) >= m) incl += o;
    }
    __shared__ int wsum[2];
    if ((tid & 63) == 63) wsum[tid >> 6] = incl;
    __syncthreads();
    if (tid >= 64) incl += wsum[0];
    if (tid < NBUCK) {
        cbase[tid] = incl - v;
        cursor[tid] = incl - v;
    }
    if (tid == 127) cbase[NBUCK] = incl;
}

__global__ __launch_bounds__(256)
void coarse_scatter2(const int* __restrict__ eiA, const int* __restrict__ eiB, int E,
                     int* __restrict__ curA, unsigned int* __restrict__ bkA,
                     int* __restrict__ curB, unsigned int* __restrict__ bkB) {
    const int* src = blockIdx.y ? eiB : eiA;
    const int* dst = src + E;
    int* cursor = blockIdx.y ? curB : curA;
    unsigned int* bucketed = blockIdx.y ? bkB : bkA;
    __shared__ int lc[NBUCK];
    __shared__ int gb[NBUCK];
    for (int i = threadIdx.x; i < NBUCK; i += 256) lc[i] = 0;
    __syncthreads();
    int base = blockIdx.x * CHUNK;
    int end = min(base + CHUNK, E);
    for (int i = base + threadIdx.x; i < end; i += 256)
        atomicAdd(&lc[dst[i] >> BSHIFT], 1);
    __syncthreads();
    for (int i = threadIdx.x; i < NBUCK; i += 256) {
        int c = lc[i];
        gb[i] = c ? atomicAdd(&cursor[i], c) : 0;
        lc[i] = 0;
    }
    __syncthreads();
    for (int i = base + threadIdx.x; i < end; i += 256) {
        int d = dst[i];
        int bk = d >> BSHIFT;
        int p = atomicAdd(&lc[bk], 1);
        bucketed[(size_t)gb[bk] + p] =
            ((unsigned int)(d - (bk << BSHIFT)) << 17) | (unsigned int)src[i];
    }
}

__global__ __launch_bounds__(256)
void fine_scatter2(const unsigned int* __restrict__ bkA, const int* __restrict__ cbA,
                   int* __restrict__ offsA, int* __restrict__ ssrcA,
                   const unsigned int* __restrict__ bkB, const int* __restrict__ cbB,
                   int* __restrict__ offsB, int* __restrict__ ssrcB, int n, int E) {
    const unsigned int* bucketed = blockIdx.y ? bkB : bkA;
    const int* cbase = blockIdx.y ? cbB : cbA;
    int* offs = blockIdx.y ? offsB : offsA;
    int* ssrc = blockIdx.y ? ssrcB : ssrcA;
    int bk = blockIdx.x;
    int ebeg = cbase[bk], eend = cbase[bk + 1];
    int d0 = bk << BSHIFT;
    __shared__ int dc[BSIZE];
    __shared__ int wp[4];
    int tid = threadIdx.x;
    for (int i = tid; i < BSIZE; i += 256) dc[i] = 0;
    __syncthreads();
    for (int i = ebeg + tid; i < eend; i += 256) {
        atomicAdd(&dc[bucketed[i] >> 17], 1);
    }
    __syncthreads();
    int a = dc[2 * tid], b = dc[2 * tid + 1];
    int s = a + b;
    int incl = s;
    #pragma unroll
    for (int m = 1; m < 64; m <<= 1) {
        int o = __shfl_up(incl, m, 64);
        if ((tid & 63) >= m) incl += o;
    }
    if ((tid & 63) == 63) wp[tid >> 6] = incl;
    __syncthreads();
    int add = 0;
    for (int w0 = 0; w0 < (tid >> 6); ++w0) add += wp[w0];
    incl += add;
    int excl = incl - s;
    dc[2 * tid] = excl;
    dc[2 * tid + 1] = excl + a;
    int d = d0 + 2 * tid;
    if (d < n) offs[d] = ebeg + excl;
    if (d + 1 < n) offs[d + 1] = ebeg + excl + a;
    if (bk == (int)gridDim.x - 1 && tid == 0) offs[n] = E;
    __syncthreads();
    for (int i = ebeg + tid; i < eend; i += 256) {
        unsigned int e = bucketed[i];
        int p = atomicAdd(&dc[e >> 17], 1);
        ssrc[ebeg + p] = (int)(e & 0x1ffffu);
    }
}

// -------- aggregation: 8 destinations per wave (load-balanced), edge-parallel lane groups --------
// G = D/8 lanes per edge (16B each); EPW = 64/G edges per step; U = 6 steps in flight.

struct AggP {
    const unsigned short* xsrc;
    const int* ssrc;
    const int* offs;
    unsigned short* mean;
};

template <int D>
__global__ __launch_bounds__(256)
void agg_mean2(AggP p0, AggP p1, int n) {
    AggP P = blockIdx.y ? p1 : p0;
    constexpr int G = D / 8;
    constexpr int EPW = 64 / G;
    constexpr int U = 6;
    const int lane = threadIdx.x & 63;
    const int wv = threadIdx.x >> 6;
    const int grp = lane / G;
    const int pos = lane % G;
    const unsigned short* base = P.xsrc + pos * 8;
    const int w0 = blockIdx.x * 32 + wv * 8;

    #pragma unroll 1
    for (int d = 0; d < 8; ++d) {
        int w = w0 + d;
        if (w >= n) break;
        const int beg = P.offs[w], end = P.offs[w + 1];

        float acc[8];
        #pragma unroll
        for (int c = 0; c < 8; ++c) acc[c] = 0.0f;

        for (int e = beg; e < end; e += EPW * U) {
            int idx[U];
            float wt[U];
            #pragma unroll
            for (int u = 0; u < U; ++u) {
                int ee = e + u * EPW + grp;
                idx[u] = P.ssrc[ee < end ? ee : end - 1];
                wt[u] = (ee < end) ? 1.0f : 0.0f;
            }
            uint4v v[U];
            #pragma unroll
            for (int u = 0; u < U; ++u)
                v[u] = *(const uint4v*)(base + (size_t)idx[u] * D);
            #pragma unroll
            for (int u = 0; u < U; ++u)
                #pragma unroll
                for (int c = 0; c < 4; ++c) {
                    unsigned int q = v[u][c];
                    acc[2 * c]     = fmaf(wt[u], __uint_as_float(q << 16), acc[2 * c]);
                    acc[2 * c + 1] = fmaf(wt[u], __uint_as_float(q & 0xffff0000u), acc[2 * c + 1]);
                }
        }
        #pragma unroll
        for (int m = G; m < 64; m <<= 1)
            #pragma unroll
            for (int c = 0; c < 8; ++c)
                acc[c] += __shfl_xor(acc[c], m, 64);
        if (lane < G) {
            float inv = 1.0f / fmaxf((float)(end - beg), 1.0f);
            uint4v o;
            #pragma unroll
            for (int c = 0; c < 4; ++c)
                o[c] = ((unsigned int)f2bf(acc[2 * c + 1] * inv) << 16) | f2bf(acc[2 * c] * inv);
            *(uint4v*)(P.mean + (size_t)w * D + pos * 8) = o;
        }
    }
}

// ------- fused MFMA dual-GEMM + bias + L2-normalize + leaky_relu -------
// BM=128, BN=256, BK=32, 512 threads (8 waves: 2 row-groups x 4 col-groups).
// global_load_lds staging; linear 64B LDS rows; chunk-XOR swizzle on both sides.

struct GP {
    const unsigned short* A;
    const unsigned short* X;
    const unsigned short* Wtl;
    const unsigned short* Wtr;
    const float* bias;
    float* outf;
    unsigned short* outb;
};

template <int D, bool BF16OUT>
__global__ __launch_bounds__(512)
void mfma_gemm2(GP p0, GP p1, int n) {
    GP P = blockIdx.y ? p1 : p0;
    constexpr int BM = 128, BK = 32;
    __shared__ __align__(16) unsigned short Asl[BM * BK];     //  8 KB
    __shared__ __align__(16) unsigned short Wsl[256 * BK];    // 16 KB
    __shared__ float red[4][BM];
    __shared__ float invn[BM];

    const int tid = threadIdx.x;
    const int wid = tid >> 6;
    const int lane = tid & 63;
    const int wr = wid >> 2, wc = wid & 3;
    const int cl = lane & 15, g = lane >> 4;
    const int row0 = blockIdx.x * BM;
    const bool full = (row0 + BM <= n);

    f32x4 acc[4][4];
    #pragma unroll
    for (int m = 0; m < 4; ++m)
        #pragma unroll
        for (int nn = 0; nn < 4; ++nn)
            acc[m][nn] = (f32x4){0.f, 0.f, 0.f, 0.f};

    #pragma unroll
    for (int pass = 0; pass < 2; ++pass) {
        const unsigned short* __restrict__ M = pass ? P.X : P.A;
        const unsigned short* __restrict__ Wt = pass ? P.Wtr : P.Wtl;
        for (int k0 = 0; k0 < D; k0 += BK) {
            __syncthreads();
            if (full) {
                int r = wid * 16 + (lane >> 2);
                int c = lane & 3;
                const unsigned short* src = M + (size_t)(row0 + r) * D + k0 + ((c ^ swz(r)) << 3);
                GLDS16(src, &Asl[wid * 512]);
            } else {
                int r = tid >> 2, c = tid & 3;
                short8 v = {0, 0, 0, 0, 0, 0, 0, 0};
                if (row0 + r < n)
                    v = *(const short8*)(M + (size_t)(row0 + r) * D + k0 + ((c ^ swz(r)) << 3));
                *(short8*)(&Asl[r * 32 + (c << 3)]) = v;
            }
            #pragma unroll
            for (int q = 0; q < 2; ++q) {
                int rw = q * 128 + wid * 16 + (lane >> 2);
                int c = lane & 3;
                const unsigned short* src = Wt + (size_t)rw * D + k0 + ((c ^ swz(rw)) << 3);
                GLDS16(src, &Wsl[(q * 128 + wid * 16) * 32]);
            }
            __syncthreads();
            short8 af[4], bfr[4];
            #pragma unroll
            for (int m = 0; m < 4; ++m) {
                int R = wr * 64 + m * 16 + cl;
                af[m] = *(const short8*)(&Asl[R * 32 + ((g ^ swz(R)) << 3)]);
            }
            #pragma unroll
            for (int nn = 0; nn < 4; ++nn) {
                int C = wc * 64 + nn * 16 + cl;
                bfr[nn] = *(const short8*)(&Wsl[C * 32 + ((g ^ swz(C)) << 3)]);
            }
            #pragma unroll
            for (int m = 0; m < 4; ++m)
                #pragma unroll
                for (int nn = 0; nn < 4; ++nn)
                    acc[m][nn] = __builtin_amdgcn_mfma_f32_16x16x32_bf16(
                        af[m], bfr[nn], acc[m][nn], 0, 0, 0);
        }
    }

    // ---- epilogue: bias, row L2-norm, leaky-relu ----
    float bv[4];
    #pragma unroll
    for (int nn = 0; nn < 4; ++nn) bv[nn] = P.bias[wc * 64 + nn * 16 + cl];

    float ss[4][4];
    #pragma unroll
    for (int m = 0; m < 4; ++m)
        #pragma unroll
        for (int r = 0; r < 4; ++r) {
            float s = 0.f;
            #pragma unroll
            for (int nn = 0; nn < 4; ++nn) {
                acc[m][nn][r] += bv[nn];
                s = fmaf(acc[m][nn][r], acc[m][nn][r], s);
            }
            ss[m][r] = s;
        }
    #pragma unroll
    for (int mask = 1; mask < 16; mask <<= 1)
        #pragma unroll
        for (int m = 0; m < 4; ++m)
            #pragma unroll
            for (int r = 0; r < 4; ++r)
                ss[m][r] += __shfl_xor(ss[m][r], mask, 64);
    if (cl == 0) {
        #pragma unroll
        for (int m = 0; m < 4; ++m)
            #pragma unroll
            for (int r = 0; r < 4; ++r)
                red[wc][wr * 64 + m * 16 + g * 4 + r] = ss[m][r];
    }
    __syncthreads();
    if (tid < BM) {
        float tot = red[0][tid] + red[1][tid] + red[2][tid] + red[3][tid];
        invn[tid] = 1.0f / fmaxf(sqrtf(tot), 1e-12f);
    }
    __syncthreads();
    #pragma unroll
    for (int m = 0; m < 4; ++m)
        #pragma unroll
        for (int r = 0; r < 4; ++r) {
            int row = wr * 64 + m * 16 + g * 4 + r;
            if (row0 + row < n) {
                float iv = invn[row];
                #pragma unroll
                for (int nn = 0; nn < 4; ++nn) {
                    float o = lrelu(acc[m][nn][r] * iv);
                    size_t off = (size_t)(row0 + row) * HID_N + wc * 64 + nn * 16 + cl;
                    if constexpr (BF16OUT) P.outb[off] = f2bf(o);
                    else P.outf[off] = o;
                }
            }
        }
}

// ---------------- launcher ----------------

extern "C" void kernel_launch(void* const* d_in, const int* in_sizes, int n_in,
                              void* d_out, int out_size, void* d_ws, size_t ws_size,
                              hipStream_t stream) {
    const float* xa = (const float*)d_in[0];
    const float* xb = (const float*)d_in[1];
    const int* ei_ab = (const int*)d_in[2];
    const int* ei_ba = (const int*)d_in[3];
    const float* Wl0_ab = (const float*)d_in[4];
    const float* Wr0_ab = (const float*)d_in[5];
    const float* b0_ab = (const float*)d_in[6];
    const float* Wl0_ba = (const float*)d_in[7];
    const float* Wr0_ba = (const float*)d_in[8];
    const float* b0_ba = (const float*)d_in[9];
    const float* Wl1_ab = (const float*)d_in[10];
    const float* Wr1_ab = (const float*)d_in[11];
    const float* b1_ab = (const float*)d_in[12];
    const float* Wl1_ba = (const float*)d_in[13];
    const float* Wr1_ba = (const float*)d_in[14];
    const float* b1_ba = (const float*)d_in[15];

    float* out_a = (float*)d_out;
    float* out_b = out_a + (size_t)NA_N * HID_N;

    char* w = (char*)d_ws;
    auto carve = [&](size_t bytes) -> char* {
        char* p = w;
        w += (bytes + 255) & ~(size_t)255;
        return p;
    };
    unsigned short* agg1 = (unsigned short*)carve((size_t)NB_N * HID_N * 2);
    unsigned short* agg2 = (unsigned short*)carve((size_t)NA_N * HID_N * 2);
    unsigned int* bucketed_b = (unsigned int*)agg1;   // aliases agg1 (dead before aggs)
    unsigned int* bucketed_a = (unsigned int*)agg2;
    unsigned short* xa_bf = (unsigned short*)carve((size_t)NA_N * DIN_N * 2);
    unsigned short* xb_bf = (unsigned short*)carve((size_t)NB_N * DIN_N * 2);
    unsigned short* ha_bf = (unsigned short*)carve((size_t)NA_N * HID_N * 2);
    unsigned short* hb_bf = (unsigned short*)carve((size_t)NB_N * HID_N * 2);
    int* off_b = (int*)carve((size_t)(NB_N + 1) * 4);
    int* off_a = (int*)carve((size_t)(NA_N + 1) * 4);
    int* ghist_b = (int*)carve(2 * NBUCK * 4);
    int* ghist_a = ghist_b + NBUCK;
    int* cbase_b = (int*)carve((NBUCK + 1) * 4);
    int* cbase_a = (int*)carve((NBUCK + 1) * 4);
    int* cursor_b = (int*)carve(NBUCK * 4);
    int* cursor_a = (int*)carve(NBUCK * 4);
    int* ssrc_ab = (int*)carve((size_t)NE_N * 4);
    int* ssrc_ba = (int*)carve((size_t)NE_N * 4);
    unsigned short* wt_l0ab = (unsigned short*)carve((size_t)DIN_N * 256 * 2);
    unsigned short* wt_r0ab = (unsigned short*)carve((size_t)DIN_N * 256 * 2);
    unsigned short* wt_l0ba = (unsigned short*)carve((size_t)DIN_N * 256 * 2);
    unsigned short* wt_r0ba = (unsigned short*)carve((size_t)DIN_N * 256 * 2);
    unsigned short* wt_l1ab = (unsigned short*)carve((size_t)HID_N * 256 * 2);
    unsigned short* wt_r1ab = (unsigned short*)carve((size_t)HID_N * 256 * 2);
    unsigned short* wt_l1ba = (unsigned short*)carve((size_t)HID_N * 256 * 2);
    unsigned short* wt_r1ba = (unsigned short*)carve((size_t)HID_N * 256 * 2);

    hipMemsetAsync(ghist_b, 0, 2 * NBUCK * 4, stream);

    {
        PrepArgs A;
        A.xa = xa; A.xa_bf = xa_bf;
        A.xb = xb; A.xb_bf = xb_bf;
        A.t[0] = {Wl0_ab, wt_l0ab, DIN_N}; A.t[1] = {Wr0_ab, wt_r0ab, DIN_N};
        A.t[2] = {Wl0_ba, wt_l0ba, DIN_N}; A.t[3] = {Wr0_ba, wt_r0ba, DIN_N};
        A.t[4] = {Wl1_ab, wt_l1ab, HID_N}; A.t[5] = {Wr1_ab, wt_r1ab, HID_N};
        A.t[6] = {Wl1_ba, wt_l1ba, HID_N}; A.t[7] = {Wr1_ba, wt_r1ba, HID_N};
        A.dstA = ei_ab + NE_N; A.dstB = ei_ba + NE_N;
        A.ghA = ghist_b; A.ghB = ghist_a;
        prep_kernel<<<2 * NF_BLK + NT_BLK + NH_BLK, 256, 0, stream>>>(A);
    }

    bucket_scan2<<<2, 128, 0, stream>>>(ghist_b, cbase_b, cursor_b, ghist_a, cbase_a, cursor_a);
    {
        dim3 g(CGRID, 2);
        coarse_scatter2<<<g, 256, 0, stream>>>(ei_ab, ei_ba, NE_N,
                                               cursor_b, bucketed_b, cursor_a, bucketed_a);
    }
    {
        dim3 g(NBUCK, 2);
        fine_scatter2<<<g, 256, 0, stream>>>(bucketed_b, cbase_b, off_b, ssrc_ab,
                                             bucketed_a, cbase_a, off_a, ssrc_ba, NA_N, NE_N);
    }

    const dim3 gagg((NA_N + 31) / 32, 2);
    const dim3 ggemm((NA_N + 127) / 128, 2);

    // ---- layer 0 (D = 128): h written as bf16 ----
    agg_mean2<DIN_N><<<gagg, 256, 0, stream>>>(
        AggP{xa_bf, ssrc_ab, off_b, agg1}, AggP{xb_bf, ssrc_ba, off_a, agg2}, NA_N);
    mfma_gemm2<DIN_N, true><<<ggemm, 512, 0, stream>>>(
        GP{agg1, xb_bf, wt_l0ab, wt_r0ab, b0_ab, nullptr, hb_bf},
        GP{agg2, xa_bf, wt_l0ba, wt_r0ba, b0_ba, nullptr, ha_bf}, NA_N);

    // ---- layer 1 (D = 256): fp32 final outputs ----
    agg_mean2<HID_N><<<gagg, 256, 0, stream>>>(
        AggP{ha_bf, ssrc_ab, off_b, agg1}, AggP{hb_bf, ssrc_ba, off_a, agg2}, NA_N);
    mfma_gemm2<HID_N, false><<<ggemm, 512, 0, stream>>>(
        GP{agg1, hb_bf, wt_l1ab, wt_r1ab, b1_ab, out_b, nullptr},
        GP{agg2, ha_bf, wt_l1ba, wt_r1ba, b1_ba, out_a, nullptr}, NA_N);
}

// Round 13
// 407.994 us; speedup vs baseline: 1.6185x; 1.0355x over previous
//
#include <hip/hip_runtime.h>
#include <hip/hip_bf16.h>
#include <math.h>
#include <string.h>

#define NA_N 50000
#define NB_N 50000
#define DIN_N 128
#define HID_N 256
#define NE_N 1000000

#define BSHIFT 9
#define BSIZE (1 << BSHIFT)
#define NBUCK ((NA_N + BSIZE - 1) >> BSHIFT)       // 98
#define CHUNK 4096
#define CGRID ((NE_N + CHUNK - 1) / CHUNK)         // 245

// prep_kernel block ranges
#define NF_BLK (NA_N * DIN_N / 4 / 256)            // 6250 per array
#define NT_BLK 2048                                // 8 weights x 256
#define NH_BLK (2 * CGRID)                         // 490

typedef short short8 __attribute__((ext_vector_type(8)));
typedef float f32x4 __attribute__((ext_vector_type(4)));
typedef unsigned int uint4v __attribute__((ext_vector_type(4)));

#define GLDS16(gp, lp) __builtin_amdgcn_global_load_lds( \
    (const __attribute__((address_space(1))) void*)(gp), \
    (__attribute__((address_space(3))) void*)(lp), 16, 0, 0)

static __device__ __forceinline__ float lrelu(float x) {
    return x >= 0.0f ? x : 0.01f * x;
}

static __device__ __forceinline__ unsigned short f2bf(float f) {
    __hip_bfloat16 h = __float2bfloat16(f);   // RNE
    unsigned short u;
    memcpy(&u, &h, 2);
    return u;
}

// chunk swizzle for 64B LDS rows of 4x16B chunks (staged tiles)
static __device__ __forceinline__ int swz(int r) { return (r & 3) ^ ((r >> 2) & 3); }

// ---------------- merged prep: f2bf (2 arrays) + 8 weight transposes + 2 coarse hists ----------------

struct TW { const float* W; unsigned short* T; int D; };

struct PrepArgs {
    const float* xa; unsigned short* xa_bf;
    const float* xb; unsigned short* xb_bf;
    TW t[8];
    const int* dstA; const int* dstB;
    int* ghA; int* ghB;
};

__global__ __launch_bounds__(256)
void prep_kernel(PrepArgs A) {
    int bid = blockIdx.x;
    const int tid = threadIdx.x;
    if (bid < 2 * NF_BLK) {                        // fp32 -> bf16 convert
        int which = bid >= NF_BLK;
        const float* in = which ? A.xb : A.xa;
        unsigned short* out = which ? A.xb_bf : A.xa_bf;
        int i = (bid - which * NF_BLK) * 256 + tid;
        float4 v = ((const float4*)in)[i];
        ushort4 b;
        b.x = f2bf(v.x); b.y = f2bf(v.y); b.z = f2bf(v.z); b.w = f2bf(v.w);
        ((ushort4*)out)[i] = b;
        return;
    }
    bid -= 2 * NF_BLK;
    if (bid < NT_BLK) {                            // weight transpose W[k][c] -> T[c][k] bf16
        TW t = A.t[bid >> 8];
        int wg = (bid & 255) * 4 + (tid >> 6);
        int lane = tid & 63;
        int kchunks = t.D >> 6;
        int c = wg / kchunks;
        int kc = wg - c * kchunks;
        int k = kc * 64 + lane;
        if (c < 256) t.T[(size_t)c * t.D + k] = f2bf(t.W[(size_t)k * 256 + c]);
        return;
    }
    bid -= NT_BLK;
    {                                              // coarse hist (bucket = dst >> BSHIFT)
        int which = bid >= CGRID;
        const int* dst = which ? A.dstB : A.dstA;
        int* ghist = which ? A.ghB : A.ghA;
        int base = (bid - which * CGRID) * CHUNK;
        __shared__ int lc[NBUCK];
        for (int i = tid; i < NBUCK; i += 256) lc[i] = 0;
        __syncthreads();
        int end = min(base + CHUNK, NE_N);
        for (int i = base + tid; i < end; i += 256)
            atomicAdd(&lc[dst[i] >> BSHIFT], 1);
        __syncthreads();
        for (int i = tid; i < NBUCK; i += 256)
            if (lc[i]) atomicAdd(&ghist[i], lc[i]);
    }
}

// ---------------- bucketed CSR build (no separate scan dispatch) ----------------
// bucketed entry: (dst_local << 17) | src
// Each coarse block computes the 98-bucket exclusive scan locally (deterministic),
// and reserves via zero-initialized cdelta. fine blocks recompute ebeg from ghist.

__global__ __launch_bounds__(256)
void coarse_scatter2(const int* __restrict__ eiA, const int* __restrict__ eiB, int E,
                     const int* __restrict__ ghA, int* __restrict__ cdA, unsigned int* __restrict__ bkA,
                     const int* __restrict__ ghB, int* __restrict__ cdB, unsigned int* __restrict__ bkB) {
    const int* src = blockIdx.y ? eiB : eiA;
    const int* dst = src + E;
    const int* ghist = blockIdx.y ? ghB : ghA;
    int* cdelta = blockIdx.y ? cdB : cdA;
    unsigned int* bucketed = blockIdx.y ? bkB : bkA;
    const int tid = threadIdx.x;

    __shared__ int cbl[NBUCK];     // local exclusive scan of ghist
    __shared__ int wsum[4];
    __shared__ int lc[NBUCK];
    __shared__ int gb[NBUCK];
    {
        int v = (tid < NBUCK) ? ghist[tid] : 0;
        int incl = v;
        #pragma unroll
        for (int m = 1; m < 64; m <<= 1) {
            int o = __shfl_up(incl, m, 64);
            if ((tid & 63) >= m) incl += o;
        }
        if ((tid & 63) == 63) wsum[tid >> 6] = incl;
        for (int i = tid; i < NBUCK; i += 256) lc[i] = 0;
        __syncthreads();
        int add = (tid >= 64 && tid < 128) ? wsum[0] : 0;
        if (tid < NBUCK) cbl[tid] = incl + add - v;
        __syncthreads();
    }
    int base = blockIdx.x * CHUNK;
    int end = min(base + CHUNK, E);
    for (int i = base + tid; i < end; i += 256)
        atomicAdd(&lc[dst[i] >> BSHIFT], 1);
    __syncthreads();
    for (int i = tid; i < NBUCK; i += 256) {
        int c = lc[i];
        gb[i] = c ? (cbl[i] + atomicAdd(&cdelta[i], c)) : 0;
        lc[i] = 0;
    }
    __syncthreads();
    for (int i = base + tid; i < end; i += 256) {
        int d = dst[i];
        int bk = d >> BSHIFT;
        int p = atomicAdd(&lc[bk], 1);
        bucketed[(size_t)gb[bk] + p] =
            ((unsigned int)(d - (bk << BSHIFT)) << 17) | (unsigned int)src[i];
    }
}

__global__ __launch_bounds__(256)
void fine_scatter2(const unsigned int* __restrict__ bkA, const int* __restrict__ ghA,
                   int* __restrict__ offsA, int* __restrict__ ssrcA,
                   const unsigned int* __restrict__ bkB, const int* __restrict__ ghB,
                   int* __restrict__ offsB, int* __restrict__ ssrcB, int n, int E) {
    const unsigned int* bucketed = blockIdx.y ? bkB : bkA;
    const int* ghist = blockIdx.y ? ghB : ghA;
    int* offs = blockIdx.y ? offsB : offsA;
    int* ssrc = blockIdx.y ? ssrcB : ssrcA;
    int bk = blockIdx.x;
    int d0 = bk << BSHIFT;
    const int tid = threadIdx.x;
    __shared__ int dc[BSIZE];
    __shared__ int wp[4];
    __shared__ int sEbeg, sEend;
    for (int i = tid; i < BSIZE; i += 256) dc[i] = 0;
    if (tid < 64) {                               // ebeg = sum ghist[0..bk-1]
        int s = 0;
        for (int i = tid; i < bk; i += 64) s += ghist[i];
        #pragma unroll
        for (int m = 1; m < 64; m <<= 1) s += __shfl_xor(s, m, 64);
        if (tid == 0) { sEbeg = s; sEend = s + ghist[bk]; }
    }
    __syncthreads();
    const int ebeg = sEbeg, eend = sEend;
    for (int i = ebeg + tid; i < eend; i += 256) {
        atomicAdd(&dc[bucketed[i] >> 17], 1);
    }
    __syncthreads();
    int a = dc[2 * tid], b = dc[2 * tid + 1];
    int s = a + b;
    int incl = s;
    #pragma unroll
    for (int m = 1; m < 64; m <<= 1) {
        int o = __shfl_up(incl, m, 64);
        if ((tid & 63) >= m) incl += o;
    }
    if ((tid & 63) == 63) wp[tid >> 6] = incl;
    __syncthreads();
    int add = 0;
    for (int w0 = 0; w0 < (tid >> 6); ++w0) add += wp[w0];
    incl += add;
    int excl = incl - s;
    dc[2 * tid] = excl;
    dc[2 * tid + 1] = excl + a;
    int d = d0 + 2 * tid;
    if (d < n) offs[d] = ebeg + excl;
    if (d + 1 < n) offs[d + 1] = ebeg + excl + a;
    if (bk == (int)gridDim.x - 1 && tid == 0) offs[n] = E;
    __syncthreads();
    for (int i = ebeg + tid; i < eend; i += 256) {
        unsigned int e = bucketed[i];
        int p = atomicAdd(&dc[e >> 17], 1);
        ssrc[ebeg + p] = (int)(e & 0x1ffffu);
    }
}

// -------- aggregation: one wave per destination, edge-parallel lane groups --------
// G = D/8 lanes per edge (16B each); EPW = 64/G edges per step; U = 6 steps in flight.

struct AggP {
    const unsigned short* xsrc;
    const int* ssrc;
    const int* offs;
    unsigned short* mean;
};

template <int D>
__global__ __launch_bounds__(256)
void agg_mean2(AggP p0, AggP p1, int n) {
    AggP P = blockIdx.y ? p1 : p0;
    constexpr int G = D / 8;
    constexpr int EPW = 64 / G;
    constexpr int U = 6;
    int w = blockIdx.x * 4 + (threadIdx.x >> 6);
    if (w >= n) return;
    const int lane = threadIdx.x & 63;
    const int grp = lane / G;
    const int pos = lane % G;
    const int beg = P.offs[w], end = P.offs[w + 1];

    float acc[8];
    #pragma unroll
    for (int c = 0; c < 8; ++c) acc[c] = 0.0f;

    const unsigned short* base = P.xsrc + pos * 8;
    for (int e = beg; e < end; e += EPW * U) {
        int idx[U];
        float wt[U];
        #pragma unroll
        for (int u = 0; u < U; ++u) {
            int ee = e + u * EPW + grp;
            idx[u] = P.ssrc[ee < end ? ee : end - 1];
            wt[u] = (ee < end) ? 1.0f : 0.0f;
        }
        uint4v v[U];
        #pragma unroll
        for (int u = 0; u < U; ++u)
            v[u] = *(const uint4v*)(base + (size_t)idx[u] * D);
        #pragma unroll
        for (int u = 0; u < U; ++u)
            #pragma unroll
            for (int c = 0; c < 4; ++c) {
                unsigned int q = v[u][c];
                acc[2 * c]     = fmaf(wt[u], __uint_as_float(q << 16), acc[2 * c]);
                acc[2 * c + 1] = fmaf(wt[u], __uint_as_float(q & 0xffff0000u), acc[2 * c + 1]);
            }
    }
    #pragma unroll
    for (int m = G; m < 64; m <<= 1)
        #pragma unroll
        for (int c = 0; c < 8; ++c)
            acc[c] += __shfl_xor(acc[c], m, 64);
    if (lane < G) {
        float inv = 1.0f / fmaxf((float)(end - beg), 1.0f);
        uint4v o;
        #pragma unroll
        for (int c = 0; c < 4; ++c)
            o[c] = ((unsigned int)f2bf(acc[2 * c + 1] * inv) << 16) | f2bf(acc[2 * c] * inv);
        *(uint4v*)(P.mean + (size_t)w * D + pos * 8) = o;
    }
}

// ------- fused MFMA dual-GEMM + bias + L2-normalize + leaky_relu -------
// BM=128, BN=256, BK=32, 512 threads (8 waves: 2 row-groups x 4 col-groups).
// global_load_lds staging; linear 64B LDS rows; chunk-XOR swizzle on both sides.

struct GP {
    const unsigned short* A;
    const unsigned short* X;
    const unsigned short* Wtl;
    const unsigned short* Wtr;
    const float* bias;
    float* outf;
    unsigned short* outb;
};

template <int D, bool BF16OUT>
__global__ __launch_bounds__(512)
void mfma_gemm2(GP p0, GP p1, int n) {
    GP P = blockIdx.y ? p1 : p0;
    constexpr int BM = 128, BK = 32;
    __shared__ __align__(16) unsigned short Asl[BM * BK];     //  8 KB
    __shared__ __align__(16) unsigned short Wsl[256 * BK];    // 16 KB
    __shared__ float red[4][BM];
    __shared__ float invn[BM];

    const int tid = threadIdx.x;
    const int wid = tid >> 6;
    const int lane = tid & 63;
    const int wr = wid >> 2, wc = wid & 3;
    const int cl = lane & 15, g = lane >> 4;
    const int row0 = blockIdx.x * BM;
    const bool full = (row0 + BM <= n);

    f32x4 acc[4][4];
    #pragma unroll
    for (int m = 0; m < 4; ++m)
        #pragma unroll
        for (int nn = 0; nn < 4; ++nn)
            acc[m][nn] = (f32x4){0.f, 0.f, 0.f, 0.f};

    #pragma unroll
    for (int pass = 0; pass < 2; ++pass) {
        const unsigned short* __restrict__ M = pass ? P.X : P.A;
        const unsigned short* __restrict__ Wt = pass ? P.Wtr : P.Wtl;
        for (int k0 = 0; k0 < D; k0 += BK) {
            __syncthreads();
            if (full) {
                int r = wid * 16 + (lane >> 2);
                int c = lane & 3;
                const unsigned short* src = M + (size_t)(row0 + r) * D + k0 + ((c ^ swz(r)) << 3);
                GLDS16(src, &Asl[wid * 512]);
            } else {
                int r = tid >> 2, c = tid & 3;
                short8 v = {0, 0, 0, 0, 0, 0, 0, 0};
                if (row0 + r < n)
                    v = *(const short8*)(M + (size_t)(row0 + r) * D + k0 + ((c ^ swz(r)) << 3));
                *(short8*)(&Asl[r * 32 + (c << 3)]) = v;
            }
            #pragma unroll
            for (int q = 0; q < 2; ++q) {
                int rw = q * 128 + wid * 16 + (lane >> 2);
                int c = lane & 3;
                const unsigned short* src = Wt + (size_t)rw * D + k0 + ((c ^ swz(rw)) << 3);
                GLDS16(src, &Wsl[(q * 128 + wid * 16) * 32]);
            }
            __syncthreads();
            short8 af[4], bfr[4];
            #pragma unroll
            for (int m = 0; m < 4; ++m) {
                int R = wr * 64 + m * 16 + cl;
                af[m] = *(const short8*)(&Asl[R * 32 + ((g ^ swz(R)) << 3)]);
            }
            #pragma unroll
            for (int nn = 0; nn < 4; ++nn) {
                int C = wc * 64 + nn * 16 + cl;
                bfr[nn] = *(const short8*)(&Wsl[C * 32 + ((g ^ swz(C)) << 3)]);
            }
            #pragma unroll
            for (int m = 0; m < 4; ++m)
                #pragma unroll
                for (int nn = 0; nn < 4; ++nn)
                    acc[m][nn] = __builtin_amdgcn_mfma_f32_16x16x32_bf16(
                        af[m], bfr[nn], acc[m][nn], 0, 0, 0);
        }
    }

    // ---- epilogue: bias, row L2-norm, leaky-relu ----
    float bv[4];
    #pragma unroll
    for (int nn = 0; nn < 4; ++nn) bv[nn] = P.bias[wc * 64 + nn * 16 + cl];

    float ss[4][4];
    #pragma unroll
    for (int m = 0; m < 4; ++m)
        #pragma unroll
        for (int r = 0; r < 4; ++r) {
            float s = 0.f;
            #pragma unroll
            for (int nn = 0; nn < 4; ++nn) {
                acc[m][nn][r] += bv[nn];
                s = fmaf(acc[m][nn][r], acc[m][nn][r], s);
            }
            ss[m][r] = s;
        }
    #pragma unroll
    for (int mask = 1; mask < 16; mask <<= 1)
        #pragma unroll
        for (int m = 0; m < 4; ++m)
            #pragma unroll
            for (int r = 0; r < 4; ++r)
                ss[m][r] += __shfl_xor(ss[m][r], mask, 64);
    if (cl == 0) {
        #pragma unroll
        for (int m = 0; m < 4; ++m)
            #pragma unroll
            for (int r = 0; r < 4; ++r)
                red[wc][wr * 64 + m * 16 + g * 4 + r] = ss[m][r];
    }
    __syncthreads();
    if (tid < BM) {
        float tot = red[0][tid] + red[1][tid] + red[2][tid] + red[3][tid];
        invn[tid] = 1.0f / fmaxf(sqrtf(tot), 1e-12f);
    }
    __syncthreads();
    #pragma unroll
    for (int m = 0; m < 4; ++m)
        #pragma unroll
        for (int r = 0; r < 4; ++r) {
            int row = wr * 64 + m * 16 + g * 4 + r;
            if (row0 + row < n) {
                float iv = invn[row];
                #pragma unroll
                for (int nn = 0; nn < 4; ++nn) {
                    float o = lrelu(acc[m][nn][r] * iv);
                    size_t off = (size_t)(row0 + row) * HID_N + wc * 64 + nn * 16 + cl;
                    if constexpr (BF16OUT) P.outb[off] = f2bf(o);
                    else P.outf[off] = o;
                }
            }
        }
}

// ---------------- launcher ----------------

extern "C" void kernel_launch(void* const* d_in, const int* in_sizes, int n_in,
                              void* d_out, int out_size, void* d_ws, size_t ws_size,
                              hipStream_t stream) {
    const float* xa = (const float*)d_in[0];
    const float* xb = (const float*)d_in[1];
    const int* ei_ab = (const int*)d_in[2];
    const int* ei_ba = (const int*)d_in[3];
    const float* Wl0_ab = (const float*)d_in[4];
    const float* Wr0_ab = (const float*)d_in[5];
    const float* b0_ab = (const float*)d_in[6];
    const float* Wl0_ba = (const float*)d_in[7];
    const float* Wr0_ba = (const float*)d_in[8];
    const float* b0_ba = (const float*)d_in[9];
    const float* Wl1_ab = (const float*)d_in[10];
    const float* Wr1_ab = (const float*)d_in[11];
    const float* b1_ab = (const float*)d_in[12];
    const float* Wl1_ba = (const float*)d_in[13];
    const float* Wr1_ba = (const float*)d_in[14];
    const float* b1_ba = (const float*)d_in[15];

    float* out_a = (float*)d_out;
    float* out_b = out_a + (size_t)NA_N * HID_N;

    char* w = (char*)d_ws;
    auto carve = [&](size_t bytes) -> char* {
        char* p = w;
        w += (bytes + 255) & ~(size_t)255;
        return p;
    };
    unsigned short* agg1 = (unsigned short*)carve((size_t)NB_N * HID_N * 2);
    unsigned short* agg2 = (unsigned short*)carve((size_t)NA_N * HID_N * 2);
    unsigned int* bucketed_b = (unsigned int*)agg1;   // aliases agg1 (dead before aggs)
    unsigned int* bucketed_a = (unsigned int*)agg2;
    unsigned short* xa_bf = (unsigned short*)carve((size_t)NA_N * DIN_N * 2);
    unsigned short* xb_bf = (unsigned short*)carve((size_t)NB_N * DIN_N * 2);
    unsigned short* ha_bf = (unsigned short*)carve((size_t)NA_N * HID_N * 2);
    unsigned short* hb_bf = (unsigned short*)carve((size_t)NB_N * HID_N * 2);
    int* off_b = (int*)carve((size_t)(NB_N + 1) * 4);
    int* off_a = (int*)carve((size_t)(NA_N + 1) * 4);
    int* ghist_b = (int*)carve(4 * NBUCK * 4);     // ghist_b, ghist_a, cdelta_b, cdelta_a
    int* ghist_a = ghist_b + NBUCK;
    int* cdelta_b = ghist_b + 2 * NBUCK;
    int* cdelta_a = ghist_b + 3 * NBUCK;
    int* ssrc_ab = (int*)carve((size_t)NE_N * 4);
    int* ssrc_ba = (int*)carve((size_t)NE_N * 4);
    unsigned short* wt_l0ab = (unsigned short*)carve((size_t)DIN_N * 256 * 2);
    unsigned short* wt_r0ab = (unsigned short*)carve((size_t)DIN_N * 256 * 2);
    unsigned short* wt_l0ba = (unsigned short*)carve((size_t)DIN_N * 256 * 2);
    unsigned short* wt_r0ba = (unsigned short*)carve((size_t)DIN_N * 256 * 2);
    unsigned short* wt_l1ab = (unsigned short*)carve((size_t)HID_N * 256 * 2);
    unsigned short* wt_r1ab = (unsigned short*)carve((size_t)HID_N * 256 * 2);
    unsigned short* wt_l1ba = (unsigned short*)carve((size_t)HID_N * 256 * 2);
    unsigned short* wt_r1ba = (unsigned short*)carve((size_t)HID_N * 256 * 2);

    hipMemsetAsync(ghist_b, 0, 4 * NBUCK * 4, stream);

    {
        PrepArgs A;
        A.xa = xa; A.xa_bf = xa_bf;
        A.xb = xb; A.xb_bf = xb_bf;
        A.t[0] = {Wl0_ab, wt_l0ab, DIN_N}; A.t[1] = {Wr0_ab, wt_r0ab, DIN_N};
        A.t[2] = {Wl0_ba, wt_l0ba, DIN_N}; A.t[3] = {Wr0_ba, wt_r0ba, DIN_N};
        A.t[4] = {Wl1_ab, wt_l1ab, HID_N}; A.t[5] = {Wr1_ab, wt_r1ab, HID_N};
        A.t[6] = {Wl1_ba, wt_l1ba, HID_N}; A.t[7] = {Wr1_ba, wt_r1ba, HID_N};
        A.dstA = ei_ab + NE_N; A.dstB = ei_ba + NE_N;
        A.ghA = ghist_b; A.ghB = ghist_a;
        prep_kernel<<<2 * NF_BLK + NT_BLK + NH_BLK, 256, 0, stream>>>(A);
    }

    {
        dim3 g(CGRID, 2);
        coarse_scatter2<<<g, 256, 0, stream>>>(ei_ab, ei_ba, NE_N,
                                               ghist_b, cdelta_b, bucketed_b,
                                               ghist_a, cdelta_a, bucketed_a);
    }
    {
        dim3 g(NBUCK, 2);
        fine_scatter2<<<g, 256, 0, stream>>>(bucketed_b, ghist_b, off_b, ssrc_ab,
                                             bucketed_a, ghist_a, off_a, ssrc_ba, NA_N, NE_N);
    }

    const dim3 gagg((NA_N + 3) / 4, 2);
    const dim3 ggemm((NA_N + 127) / 128, 2);

    // ---- layer 0 (D = 128): h written as bf16 ----
    agg_mean2<DIN_N><<<gagg, 256, 0, stream>>>(
        AggP{xa_bf, ssrc_ab, off_b, agg1}, AggP{xb_bf, ssrc_ba, off_a, agg2}, NA_N);
    mfma_gemm2<DIN_N, true><<<ggemm, 512, 0, stream>>>(
        GP{agg1, xb_bf, wt_l0ab, wt_r0ab, b0_ab, nullptr, hb_bf},
        GP{agg2, xa_bf, wt_l0ba, wt_r0ba, b0_ba, nullptr, ha_bf}, NA_N);

    // ---- layer 1 (D = 256): fp32 final outputs ----
    agg_mean2<HID_N><<<gagg, 256, 0, stream>>>(
        AggP{ha_bf, ssrc_ab, off_b, agg1}, AggP{hb_bf, ssrc_ba, off_a, agg2}, NA_N);
    mfma_gemm2<HID_N, false><<<ggemm, 512, 0, stream>>>(
        GP{agg1, hb_bf, wt_l1ab, wt_r1ab, b1_ab, out_b, nullptr},
        GP{agg2, ha_bf, wt_l1ba, wt_r1ba, b1_ba, out_a, nullptr}, NA_N);
}